// Round 3
// baseline (124.610 us; speedup 1.0000x reference)
//
#include <hip/hip_runtime.h>

typedef __attribute__((ext_vector_type(8))) short short8;
typedef __attribute__((ext_vector_type(4))) float floatx4;

#define FDIM 512
#define HDIM 256

__device__ __forceinline__ unsigned short f2bf(float f) {
  unsigned int u = __float_as_uint(f);
  u += 0x7fffu + ((u >> 16) & 1u);   // round-to-nearest-even
  return (unsigned short)(u >> 16);
}

__device__ __forceinline__ short8 pack2(floatx4 a, floatx4 b) {
  short8 r;
  r[0] = (short)f2bf(a[0]); r[1] = (short)f2bf(a[1]);
  r[2] = (short)f2bf(a[2]); r[3] = (short)f2bf(a[3]);
  r[4] = (short)f2bf(b[0]); r[5] = (short)f2bf(b[1]);
  r[6] = (short)f2bf(b[2]); r[7] = (short)f2bf(b[3]);
  return r;
}

__device__ __forceinline__ float fast_tanh(float x) {
  x = fminf(15.0f, fmaxf(-15.0f, x));
  float e = __expf(2.0f * x);
  return (e - 1.0f) / (e + 1.0f);
}

// A: 2 x global_load_dwordx4 (8 floats), counted in the manual vmcnt ledger.
#define GLOAD_A(r0, r1, p)                                                     \
  do {                                                                         \
    asm volatile("global_load_dwordx4 %0, %1, off"                             \
                 : "=v"(r0) : "v"(p) : "memory");                              \
    asm volatile("global_load_dwordx4 %0, %1, off offset:16"                   \
                 : "=v"(r1) : "v"(p) : "memory");                              \
  } while (0)

// B: 4 x global_load_dwordx4 (4 short8 fragments, nf stride = 256 B).
#define GLOAD_B(r, p)                                                          \
  do {                                                                         \
    asm volatile("global_load_dwordx4 %0, %1, off"                             \
                 : "=v"(r[0]) : "v"(p) : "memory");                            \
    asm volatile("global_load_dwordx4 %0, %1, off offset:256"                  \
                 : "=v"(r[1]) : "v"(p) : "memory");                            \
    asm volatile("global_load_dwordx4 %0, %1, off offset:512"                  \
                 : "=v"(r[2]) : "v"(p) : "memory");                            \
    asm volatile("global_load_dwordx4 %0, %1, off offset:768"                  \
                 : "=v"(r[3]) : "v"(p) : "memory");                            \
  } while (0)

// K0: pack W1 [512][256] fp32 -> W1B bf16 fragment-major:
// element index = s*8192 + oct*2048 + n*8 + e   (k = s*32 + oct*8 + e)
// Blocks < 128 also zero out (re-poison safety; out accumulated by atomics).
__global__ void __launch_bounds__(256)
k0_pack_w1(const float* __restrict__ W1, unsigned short* __restrict__ W1B,
           float* __restrict__ out) {
  int tid = threadIdx.x;
  int idx = blockIdx.x * 256 + tid;           // 0..131071
  if (blockIdx.x < 128) out[blockIdx.x * 256 + tid] = 0.0f;   // 32768 floats
  int k = idx >> 8;                           // 0..511
  int n = idx & 255;
  int s = k >> 5, r = k & 31, oct = r >> 3, e = r & 7;
  W1B[s * 8192 + oct * 2048 + n * 8 + e] = f2bf(W1[idx]);
}

// K1 fused: scores + exp + UNNORMALIZED per-bag weighted sum of X.
// 64 rows/block, 4 waves (each wave = one 64-col group), BK=32, 16 steps.
// As (bf16 X tile) = 64 KB; B lives in REGISTERS (3 rotating sets, depth-2
// prefetch from fragment-major W1B, L2-hot) -> LDS/block ~66.8 KB ->
// 2 independent blocks/CU so barrier stalls of one block hide under the other.
// vmcnt ledger (per wave, in-order): per step issue A(t+2):2 + B(t+2):4.
//   step t head (steady): [A(t)2, B(t)4, A(t+1)2, B(t+1)4] = 12
//     vmcnt(10) -> A(t) regs ready (pack + ds_write)
//   after barrier + issue(6): 16 outstanding; vmcnt(12) -> B(t) regs ready
//   tails: t=14: no issue, B-wait vmcnt(6); t=15: head vmcnt(4), B-wait vmcnt(0)
// Hazards: As slots write-once (no WAR); one barrier/step for write->read
// visibility (lgkmcnt(0) before it). B reg sets rotate mod 3: B(t+2)'s set
// held B(t-1), consumed at step t-1 before the issue point. scpart/es_s are
// separate LDS (no aliasing).
__global__ void __launch_bounds__(256, 2)
k1_fused(const float* __restrict__ X,
         const unsigned short* __restrict__ W1B,
         const float* __restrict__ b1,
         const float* __restrict__ W2,
         const int* __restrict__ bag_sizes,
         int nbags,
         float* __restrict__ out,
         float* __restrict__ partials) {
  __shared__ __align__(16) unsigned char smem[66816];
  unsigned short* As = (unsigned short*)smem;        // [slot 64][row 64][e 8] = 64 KB
  float* scpart = (float*)(smem + 65536);            // [4][64]
  float* es_s   = (float*)(smem + 66560);            // [64]

  const int tid  = threadIdx.x;
  const int wn   = tid >> 6;          // 0..3 col-group
  const int lane = tid & 63;
  const int l15  = lane & 15;
  const int l4   = lane >> 4;
  const long row0 = (long)blockIdx.x * 64;

  floatx4 acc[4][4];
  #pragma unroll
  for (int m = 0; m < 4; m++)
    #pragma unroll
    for (int n = 0; n < 4; n++)
      acc[m][n] = (floatx4){0.f, 0.f, 0.f, 0.f};

  // A staging map: thread -> (row = tid>>2, octet = tid&3 -> 8 consecutive k)
  const int arow = tid >> 2;                    // 0..63
  const int aoct = tid & 3;                     // octet within 32-k step
  const float* xsrc = X + (row0 + arow) * FDIM + aoct * 8;
  // B fragment base for this lane (elements): oct=l4, col=wn*64+l15
  const unsigned short* bsrc = W1B + l4 * 2048 + (wn * 64 + l15) * 8;

  floatx4 va0, va1, vb0, vb1;            // 2 rotating A sets (depth-2)
  short8 br0[4], br1[4], br2[4];         // 3 rotating B sets (depth-2)

  // Prologue issue order: A(0), B(0)->set0, A(1), B(1)->set1  => 12 outstanding
  GLOAD_A(va0, va1, xsrc);
  GLOAD_B(br0, bsrc);
  GLOAD_A(vb0, vb1, xsrc + 32);
  GLOAD_B(br1, bsrc + 8192);

  #pragma unroll
  for (int t = 0; t < 16; ++t) {
    // ---- retire A(t) regs ----
    if (t < 15) asm volatile("s_waitcnt vmcnt(10)" ::: "memory");
    else        asm volatile("s_waitcnt vmcnt(4)" ::: "memory");
    __builtin_amdgcn_sched_barrier(0);
    {
      short8 a = ((t & 1) == 0) ? pack2(va0, va1) : pack2(vb0, vb1);
      int slot = t * 4 + aoct;
      *(short8*)(As + (slot * 64 + (arow ^ (slot & 7))) * 8) = a;
    }
    asm volatile("s_waitcnt lgkmcnt(0)" ::: "memory");
    __builtin_amdgcn_sched_barrier(0);
    __builtin_amdgcn_s_barrier();
    // ---- issue next-tile loads (stay in flight across barriers) ----
    if (t < 14) {
      const float* pp = xsrc + (t + 2) * 32;
      if ((t & 1) == 0) GLOAD_A(va0, va1, pp);
      else              GLOAD_A(vb0, vb1, pp);
      const unsigned short* bp = bsrc + (t + 2) * 8192;
      if (((t + 2) % 3) == 0)      GLOAD_B(br0, bp);
      else if (((t + 2) % 3) == 1) GLOAD_B(br1, bp);
      else                         GLOAD_B(br2, bp);
    }
    // ---- retire B(t) regs ----
    if (t < 14)       asm volatile("s_waitcnt vmcnt(12)" ::: "memory");
    else if (t == 14) asm volatile("s_waitcnt vmcnt(6)" ::: "memory");
    else              asm volatile("s_waitcnt vmcnt(0)" ::: "memory");
    __builtin_amdgcn_sched_barrier(0);
    // ---- compute(t): 4 A-frags x 4 B-frags, 16 MFMA per wave ----
    const int slotc = t * 4 + l4;
    const int gg = slotc & 7;
    short8 af[4];
    #pragma unroll
    for (int m = 0; m < 4; ++m)
      af[m] = *(const short8*)(As + (slotc * 64 + ((m * 16 + l15) ^ gg)) * 8);
    const short8* bcur = ((t % 3) == 0) ? br0 : ((t % 3) == 1) ? br1 : br2;
    #pragma unroll
    for (int n = 0; n < 4; ++n)
      #pragma unroll
      for (int m = 0; m < 4; ++m)
        acc[m][n] = __builtin_amdgcn_mfma_f32_16x16x32_bf16(af[m], bcur[n], acc[m][n], 0, 0, 0);
  }

  // epilogue: score = sum_c tanh(H + b1[c]) * W2[c]  over this wave's 64 cols
  float rowacc[16];
  #pragma unroll
  for (int i = 0; i < 16; i++) rowacc[i] = 0.f;
  #pragma unroll
  for (int n = 0; n < 4; n++) {
    int c = wn * 64 + n * 16 + l15;
    float b1c = b1[c];
    float w2c = W2[c];
    #pragma unroll
    for (int m = 0; m < 4; m++)
      #pragma unroll
      for (int j = 0; j < 4; j++) {
        float h = fast_tanh(acc[m][n][j] + b1c);
        rowacc[m * 4 + j] = fmaf(h, w2c, rowacc[m * 4 + j]);
      }
  }
  #pragma unroll
  for (int i = 0; i < 16; i++) {
    float v = rowacc[i];
    v += __shfl_xor(v, 1, 64);
    v += __shfl_xor(v, 2, 64);
    v += __shfl_xor(v, 4, 64);
    v += __shfl_xor(v, 8, 64);
    rowacc[i] = v;
  }
  if (l15 == 0) {
    #pragma unroll
    for (int m = 0; m < 4; m++)
      #pragma unroll
      for (int j = 0; j < 4; j++)
        scpart[wn * 64 + m * 16 + l4 * 4 + j] = rowacc[m * 4 + j];
  }
  __syncthreads();

  // es (LDS only) + block partial Z  (single wave: tid 0..63)
  if (tid < 64) {
    float sv = scpart[0 * 64 + tid] + scpart[1 * 64 + tid] +
               scpart[2 * 64 + tid] + scpart[3 * 64 + tid];
    float ev = __expf(sv);
    es_s[tid] = ev;
    float v = ev;
    v += __shfl_xor(v, 1, 64);
    v += __shfl_xor(v, 2, 64);
    v += __shfl_xor(v, 4, 64);
    v += __shfl_xor(v, 8, 64);
    v += __shfl_xor(v, 16, 64);
    v += __shfl_xor(v, 32, 64);
    if (tid == 0) partials[blockIdx.x] = v;
  }
  __syncthreads();

  // ---- phase 2: out[bag] += sum_r es[r] * X_bf16[r]  (unnormalized) ----
  // thread = (chunk s 0..63 = 8 features, parity p 0..3 over rows)
  const int s  = tid >> 2;
  const int p  = tid & 3;
  const int gp = s & 7;                          // As row-swizzle for this slot
  const int fbase = (s >> 2) * 32 + (s & 3) * 8; // k = (s>>2)*32 + (s&3)*8 + e
  const unsigned short* abase = As + s * 512;

  // bag of first row (uniform across block)
  int bag = 0; long cum = 0;
  while (bag + 1 < nbags && cum + (long)bag_sizes[bag] <= row0) {
    cum += bag_sizes[bag]; ++bag;
  }
  long bagEnd = cum + (long)bag_sizes[bag];

  int rs = 0;
  while (rs < 64) {
    int se = (int)(bagEnd - row0 < 64 ? bagEnd - row0 : 64);
    float pa[8];
    #pragma unroll
    for (int e = 0; e < 8; ++e) pa[e] = 0.f;
    #pragma unroll
    for (int j = 0; j < 16; ++j) {
      int r = p + 4 * j;
      if (r >= rs && r < se) {
        float w = es_s[r];
        short8 xv = *(const short8*)(abase + ((r ^ gp) * 8));
        const unsigned int* ui = (const unsigned int*)&xv;
        #pragma unroll
        for (int d = 0; d < 4; ++d) {
          float xlo = __uint_as_float(ui[d] << 16);
          float xhi = __uint_as_float(ui[d] & 0xffff0000u);
          pa[2 * d]     = fmaf(xlo, w, pa[2 * d]);
          pa[2 * d + 1] = fmaf(xhi, w, pa[2 * d + 1]);
        }
      }
    }
    // reduce over parity p (lane bits 0..1; same s)
    #pragma unroll
    for (int e = 0; e < 8; ++e) {
      pa[e] += __shfl_xor(pa[e], 1, 64);
      pa[e] += __shfl_xor(pa[e], 2, 64);
    }
    if (p == 0 && se > rs) {
      float* op = out + (long)bag * FDIM + fbase;
      #pragma unroll
      for (int e = 0; e < 8; ++e) atomicAdd(op + e, pa[e]);
    }
    rs = se;
    if (rs < 64) {
      ++bag;
      if (bag >= nbags) { bagEnd = row0 + 64; bag = nbags - 1; }
      else bagEnd += (long)bag_sizes[bag];
    }
  }
}

// K2: Z = sum(partials) (redundant per block); out *= 1/Z
__global__ void __launch_bounds__(256)
k2_scale(const float* __restrict__ partials, int nparts, float* __restrict__ out) {
  __shared__ float wred[4];
  int tid = threadIdx.x;
  float sL = 0.f;
  for (int j = tid; j < nparts; j += 256) sL += partials[j];
  #pragma unroll
  for (int m = 1; m < 64; m <<= 1) sL += __shfl_xor(sL, m, 64);
  if ((tid & 63) == 0) wred[tid >> 6] = sL;
  __syncthreads();
  float invZ = 1.0f / (wred[0] + wred[1] + wred[2] + wred[3]);
  int i = blockIdx.x * 256 + tid;
  out[i] = out[i] * invZ;
}

extern "C" void kernel_launch(void* const* d_in, const int* in_sizes, int n_in,
                              void* d_out, int out_size, void* d_ws, size_t ws_size,
                              hipStream_t stream) {
  const float* X         = (const float*)d_in[0];
  const int*   bag_sizes = (const int*)d_in[1];
  const float* W1        = (const float*)d_in[2];
  const float* b1        = (const float*)d_in[3];
  const float* W2        = (const float*)d_in[4];
  // b2 (d_in[5]) cancels in the global softmax — unused.
  float* out = (float*)d_out;

  const int T     = in_sizes[0] / FDIM;   // 131072
  const int nbags = in_sizes[1];          // 64
  const int nblk  = T / 64;               // 2048

  char* ws = (char*)d_ws;
  unsigned short* W1B = (unsigned short*)ws;                     // 262144 B
  float* partials = (float*)(ws + 262144);                       // 8192 B

  hipLaunchKernelGGL(k0_pack_w1, dim3(512), dim3(256), 0, stream, W1, W1B, out);
  hipLaunchKernelGGL(k1_fused, dim3(nblk), dim3(256), 0, stream,
                     X, W1B, b1, W2, bag_sizes, nbags, out, partials);
  hipLaunchKernelGGL(k2_scale, dim3((nbags * FDIM) / 256), dim3(256), 0, stream,
                     partials, nblk, out);
}

// Round 5
// 107.141 us; speedup vs baseline: 1.1630x; 1.1630x over previous
//
#include <hip/hip_runtime.h>

typedef __attribute__((ext_vector_type(8))) short short8;
typedef __attribute__((ext_vector_type(4))) float floatx4;

#define FDIM 512
#define HDIM 256

__device__ __forceinline__ unsigned short f2bf(float f) {
  unsigned int u = __float_as_uint(f);
  u += 0x7fffu + ((u >> 16) & 1u);   // round-to-nearest-even
  return (unsigned short)(u >> 16);
}

__device__ __forceinline__ short8 pack2(floatx4 a, floatx4 b) {
  short8 r;
  r[0] = (short)f2bf(a[0]); r[1] = (short)f2bf(a[1]);
  r[2] = (short)f2bf(a[2]); r[3] = (short)f2bf(a[3]);
  r[4] = (short)f2bf(b[0]); r[5] = (short)f2bf(b[1]);
  r[6] = (short)f2bf(b[2]); r[7] = (short)f2bf(b[3]);
  return r;
}

__device__ __forceinline__ float fast_tanh(float x) {
  x = fminf(15.0f, fmaxf(-15.0f, x));
  float e = __expf(2.0f * x);
  return (e - 1.0f) / (e + 1.0f);
}

// A: 2 x global_load_dwordx4 (8 floats), counted in the manual vmcnt ledger.
#define GLOAD_A(r0, r1, p)                                                     \
  do {                                                                         \
    asm volatile("global_load_dwordx4 %0, %1, off"                             \
                 : "=v"(r0) : "v"(p) : "memory");                              \
    asm volatile("global_load_dwordx4 %0, %1, off offset:16"                   \
                 : "=v"(r1) : "v"(p) : "memory");                              \
  } while (0)

// B: 4 x global_load_dwordx4 (4 short8 fragments, 16-col stride = 256 B).
#define GLOAD_B(r, p)                                                          \
  do {                                                                         \
    asm volatile("global_load_dwordx4 %0, %1, off"                             \
                 : "=v"(r[0]) : "v"(p) : "memory");                            \
    asm volatile("global_load_dwordx4 %0, %1, off offset:256"                  \
                 : "=v"(r[1]) : "v"(p) : "memory");                            \
    asm volatile("global_load_dwordx4 %0, %1, off offset:512"                  \
                 : "=v"(r[2]) : "v"(p) : "memory");                            \
    asm volatile("global_load_dwordx4 %0, %1, off offset:768"                  \
                 : "=v"(r[3]) : "v"(p) : "memory");                            \
  } while (0)

// K0: pack W1 [512][256] fp32 -> W1B bf16 fragment-major:
// element index = s*8192 + oct*2048 + n*8 + e   (k = s*32 + oct*8 + e)
// Blocks < 128 also zero out (re-poison safety; out accumulated by atomics).
__global__ void __launch_bounds__(256)
k0_pack_w1(const float* __restrict__ W1, unsigned short* __restrict__ W1B,
           float* __restrict__ out) {
  int tid = threadIdx.x;
  int idx = blockIdx.x * 256 + tid;           // 0..131071
  if (blockIdx.x < 128) out[blockIdx.x * 256 + tid] = 0.0f;   // 32768 floats
  int k = idx >> 8;                           // 0..511
  int n = idx & 255;
  int s = k >> 5, r = k & 31, oct = r >> 3, e = r & 7;
  W1B[s * 8192 + oct * 2048 + n * 8 + e] = f2bf(W1[idx]);
}

// K1: es = exp(score) per row + per-block partial Z.  SCORES ONLY.
// 64 rows/block, 4 waves (wave = 64-col group), BK=32, 16 steps.
// LDS ~9 KB (double-buffered row-major A tile); B in registers.
// SPILL SAFETY (round-4 lesson): NO min-waves launch bound — a VGPR cap
// below live demand makes the allocator spill in-flight asm-load registers
// and scratch ops corrupt the manual vmcnt ledger (silent data corruption).
// Demand ~140 VGPR << 256 cap -> no spill; actual use still gives
// ~3 waves/SIMD = 3 independent blocks/CU for barrier decoupling.
// vmcnt ledger (per thread, in-order; A=2 instr, B=4 instr, B depth-1,
// A depth-2):  prologue: A(0) B(0) A(1) = 8 outstanding.
//   step t head: [A(t)2 B(t)4 A(t+1)2] -> vmcnt(6) retires A(t)
//     (t=15: [A15 B15] -> vmcnt(4))
//   after barrier: issue B(t+1) (t<15) then A(t+2) (t<14) -> 12 outstanding
//   compute wait: vmcnt(8) retires B(t)   (t=14: vmcnt(6); t=15: vmcnt(0))
// B sets rotate (t&1): B(t+1) lands in set (t+1)&1, compute(t) reads t&1.
// WAR on As[t&1]: readers of step t-2 drain via own lgkmcnt(0) before
// barrier(t-1); writer passes barrier(t-1) first -> one barrier/step safe.
__global__ void __launch_bounds__(256, 2)
k1_scores(const float* __restrict__ X,
          const unsigned short* __restrict__ W1B,
          const float* __restrict__ b1,
          const float* __restrict__ W2,
          float* __restrict__ es,
          float* __restrict__ partials) {
  __shared__ __align__(16) unsigned short As[2][2048];  // [buf][row64*32k] = 8 KB
  __shared__ float scpart[256];                         // [wn][row64]

  const int tid  = threadIdx.x;
  const int wn   = tid >> 6;          // 0..3 col-group
  const int lane = tid & 63;
  const int l15  = lane & 15;
  const int l4   = lane >> 4;
  const long row0 = (long)blockIdx.x * 64;

  floatx4 acc[4][4];
  #pragma unroll
  for (int m = 0; m < 4; m++)
    #pragma unroll
    for (int n = 0; n < 4; n++)
      acc[m][n] = (floatx4){0.f, 0.f, 0.f, 0.f};

  // A staging map: thread -> (row = tid>>2, octet = tid&3 -> 8 consecutive k)
  const int arow = tid >> 2;                    // 0..63
  const int aoct = tid & 3;                     // octet within 32-k step
  const float* xsrc = X + (row0 + arow) * FDIM + aoct * 8;
  // B fragment base for this lane: oct = l4, col = wn*64 + l15
  const unsigned short* bsrc = W1B + l4 * 2048 + (wn * 64 + l15) * 8;

  floatx4 va0, va1, vb0, vb1;            // 2 rotating A sets (depth-2)
  short8 br0[4], br1[4];                 // 2 rotating B sets (depth-1)

  // Prologue issue order: A(0), B(0)->set0, A(1)  => 8 outstanding
  GLOAD_A(va0, va1, xsrc);
  GLOAD_B(br0, bsrc);
  GLOAD_A(vb0, vb1, xsrc + 32);

  #pragma unroll
  for (int t = 0; t < 16; ++t) {
    // ---- retire A(t) regs ----
    if (t < 15) asm volatile("s_waitcnt vmcnt(6)" ::: "memory");
    else        asm volatile("s_waitcnt vmcnt(4)" ::: "memory");
    __builtin_amdgcn_sched_barrier(0);
    {
      short8 a = ((t & 1) == 0) ? pack2(va0, va1) : pack2(vb0, vb1);
      *(short8*)(&As[t & 1][arow * 32 + aoct * 8]) = a;
    }
    asm volatile("s_waitcnt lgkmcnt(0)" ::: "memory");
    __builtin_amdgcn_sched_barrier(0);
    __builtin_amdgcn_s_barrier();
    // ---- issue next loads (stay in flight across barriers) ----
    if (t < 15) {                       // B(t+1) -> other set
      const unsigned short* bp = bsrc + (t + 1) * 8192;
      if (((t + 1) & 1) == 0) GLOAD_B(br0, bp);
      else                    GLOAD_B(br1, bp);
    }
    if (t < 14) {                       // A(t+2) -> just-consumed set
      const float* pp = xsrc + (t + 2) * 32;
      if ((t & 1) == 0) GLOAD_A(va0, va1, pp);
      else              GLOAD_A(vb0, vb1, pp);
    }
    // ---- retire B(t) regs ----
    if (t < 14)       asm volatile("s_waitcnt vmcnt(8)" ::: "memory");
    else if (t == 14) asm volatile("s_waitcnt vmcnt(6)" ::: "memory");
    else              asm volatile("s_waitcnt vmcnt(0)" ::: "memory");
    __builtin_amdgcn_sched_barrier(0);
    // ---- compute(t): 4 A-frags x 4 B-frags, 16 MFMA per wave ----
    short8 af[4];
    #pragma unroll
    for (int m = 0; m < 4; ++m)
      af[m] = *(const short8*)(&As[t & 1][(m * 16 + l15) * 32 + l4 * 8]);
    const short8* bcur = ((t & 1) == 0) ? br0 : br1;
    #pragma unroll
    for (int n = 0; n < 4; ++n)
      #pragma unroll
      for (int m = 0; m < 4; ++m)
        acc[m][n] = __builtin_amdgcn_mfma_f32_16x16x32_bf16(af[m], bcur[n], acc[m][n], 0, 0, 0);
  }

  // epilogue: score = sum_c tanh(H + b1[c]) * W2[c]  over this wave's 64 cols
  float rowacc[16];
  #pragma unroll
  for (int i = 0; i < 16; i++) rowacc[i] = 0.f;
  #pragma unroll
  for (int n = 0; n < 4; n++) {
    int c = wn * 64 + n * 16 + l15;
    float b1c = b1[c];
    float w2c = W2[c];
    #pragma unroll
    for (int m = 0; m < 4; m++)
      #pragma unroll
      for (int j = 0; j < 4; j++) {
        float h = fast_tanh(acc[m][n][j] + b1c);
        rowacc[m * 4 + j] = fmaf(h, w2c, rowacc[m * 4 + j]);
      }
  }
  #pragma unroll
  for (int i = 0; i < 16; i++) {
    float v = rowacc[i];
    v += __shfl_xor(v, 1, 64);
    v += __shfl_xor(v, 2, 64);
    v += __shfl_xor(v, 4, 64);
    v += __shfl_xor(v, 8, 64);
    rowacc[i] = v;
  }
  if (l15 == 0) {
    #pragma unroll
    for (int m = 0; m < 4; m++)
      #pragma unroll
      for (int j = 0; j < 4; j++)
        scpart[wn * 64 + m * 16 + l4 * 4 + j] = rowacc[m * 4 + j];
  }
  __syncthreads();

  // es (global) + block partial Z  (first wave only)
  if (tid < 64) {
    float sv = scpart[0 * 64 + tid] + scpart[1 * 64 + tid] +
               scpart[2 * 64 + tid] + scpart[3 * 64 + tid];
    float ev = __expf(sv);
    es[row0 + tid] = ev;
    float v = ev;
    v += __shfl_xor(v, 1, 64);
    v += __shfl_xor(v, 2, 64);
    v += __shfl_xor(v, 4, 64);
    v += __shfl_xor(v, 8, 64);
    v += __shfl_xor(v, 16, 64);
    v += __shfl_xor(v, 32, 64);
    if (tid == 0) partials[blockIdx.x] = v;
  }
}

// K2b: invZ = 1 / sum(partials)
__global__ void __launch_bounds__(256)
k2b_finish(const float* __restrict__ partials, int nparts, float* __restrict__ invZ) {
  int tid = threadIdx.x;
  float s = 0.f;
  for (int j = tid; j < nparts; j += 256) s += partials[j];
  #pragma unroll
  for (int m = 1; m < 64; m <<= 1) s += __shfl_xor(s, m, 64);
  __shared__ float wred[4];
  if ((tid & 63) == 0) wred[tid >> 6] = s;
  __syncthreads();
  if (tid == 0) invZ[0] = 1.0f / (wred[0] + wred[1] + wred[2] + wred[3]);
}

// K3: out[bag] += invZ * sum_{i in chunk} es[i] * X[i]   (fp32 X, L3-warm)
// 16 chunks per bag; 256 threads = 128 feature-float4 x 2 row-parities.
__global__ void __launch_bounds__(256)
k3_bagsum(const float* __restrict__ X, const int* __restrict__ bag_sizes,
          const float* __restrict__ es, const float* __restrict__ invZp,
          float* __restrict__ out, int nbags) {
  const int tid = threadIdx.x;
  const int f   = (tid & 127) * 4;     // 0..508
  const int r   = tid >> 7;            // 0 or 1
  const int bag = blockIdx.x >> 4;
  const int ic  = blockIdx.x & 15;
  int start = 0;
  for (int b = 0; b < bag; ++b) start += bag_sizes[b];
  const int size = bag_sizes[bag];
  const int end = start + size;
  const int chunk = (size + 15) >> 4;
  int i0 = start + ic * chunk;
  int i1 = min(i0 + chunk, end);
  float ax = 0.f, ay = 0.f, az = 0.f, aw = 0.f;
  for (int i = i0 + r; i < i1; i += 2) {
    float w = es[i];
    float4 x = *(const float4*)(X + (size_t)i * FDIM + f);
    ax = fmaf(x.x, w, ax); ay = fmaf(x.y, w, ay);
    az = fmaf(x.z, w, az); aw = fmaf(x.w, w, aw);
  }
  __shared__ float4 red[128];
  if (r == 1) red[tid & 127] = (float4){ax, ay, az, aw};
  __syncthreads();
  if (r == 0) {
    float4 o = red[tid];
    float invZ = invZp[0];
    ax = (ax + o.x) * invZ; ay = (ay + o.y) * invZ;
    az = (az + o.z) * invZ; aw = (aw + o.w) * invZ;
    float* op = out + (size_t)bag * FDIM + f;
    atomicAdd(op + 0, ax); atomicAdd(op + 1, ay);
    atomicAdd(op + 2, az); atomicAdd(op + 3, aw);
  }
}

extern "C" void kernel_launch(void* const* d_in, const int* in_sizes, int n_in,
                              void* d_out, int out_size, void* d_ws, size_t ws_size,
                              hipStream_t stream) {
  const float* X         = (const float*)d_in[0];
  const int*   bag_sizes = (const int*)d_in[1];
  const float* W1        = (const float*)d_in[2];
  const float* b1        = (const float*)d_in[3];
  const float* W2        = (const float*)d_in[4];
  // b2 (d_in[5]) cancels in the global softmax — unused.
  float* out = (float*)d_out;

  const int T     = in_sizes[0] / FDIM;   // 131072
  const int nbags = in_sizes[1];          // 64
  const int nblk  = T / 64;               // 2048

  char* ws = (char*)d_ws;
  unsigned short* W1B = (unsigned short*)ws;                     // 262144 B
  float* es       = (float*)(ws + 262144);                       // 524288 B
  float* partials = (float*)(ws + 262144 + 524288);              // 8192 B
  float* invZ     = (float*)(ws + 262144 + 524288 + 8192);       // 4 B

  hipLaunchKernelGGL(k0_pack_w1, dim3(512), dim3(256), 0, stream, W1, W1B, out);
  hipLaunchKernelGGL(k1_scores, dim3(nblk), dim3(256), 0, stream,
                     X, W1B, b1, W2, es, partials);
  hipLaunchKernelGGL(k2b_finish, dim3(1), dim3(256), 0, stream, partials, nblk, invZ);
  hipLaunchKernelGGL(k3_bagsum, dim3(nbags * 16), dim3(256), 0, stream,
                     X, bag_sizes, es, invZ, out, nbags);
}